// Round 7
// baseline (6672.947 us; speedup 1.0000x reference)
//
#include <hip/hip_runtime.h>
#include <hip/hip_bf16.h>

// GRU recurrence B=128, S=512, H=1024 — chunked dataflow persistent kernel.
// 8 independent groups x 32 WGs (group = wg&7); group owns 16 batch rows; WG
// owns 32 cols. All cross-WG data via sc0+sc1 (IC-coherent, r4-proven).
// Per WG (8 waves), NO __syncthreads in steady loop:
//   waves 0,1: r = sigmoid(pxi@Ww^T) full-K chunked -> av = r*p + x, publish slot
//   waves 4,5: z = sigmoid(pxi@Uw^T) chunked; then gate-combine h -> p', out,
//              pxi' = p' + x_{t+1}, publish slot
//   waves 2,3: h-GEMM (av@Vw^T) chunked -> sc LDS handoff to 4,5
//   wave 7:    stager — polls 64 per-producer-wave slots (1 ballot load), stages
//              ready 1KB chunks into LDS in-order, bumps LDS counter
//   wave 6:    idle
// Consumers spin on LDS counters and MFMA chunk-by-chunk as data lands, so
// staging+GEMM overlap the producer arrival spread instead of following it.

#define Ss 512
#define Hh 1024
#define NWG 256
#define NTHR 512
#define LDS_TOTAL 76800

typedef __bf16 bf16x8 __attribute__((ext_vector_type(8)));
typedef float f32x4 __attribute__((ext_vector_type(4)));
typedef int   i32x4 __attribute__((ext_vector_type(4)));

__device__ __forceinline__ float sigmoid_fast(float x) { return 1.0f / (1.0f + __expf(-x)); }
__device__ __forceinline__ float tanh_fast(float x) { return 2.0f / (1.0f + __expf(-2.0f * x)) - 1.0f; }

__device__ __forceinline__ unsigned lds_ld(const unsigned* p) {
    return __hip_atomic_load(p, __ATOMIC_RELAXED, __HIP_MEMORY_SCOPE_WORKGROUP);
}
__device__ __forceinline__ void lds_st(unsigned* p, unsigned v) {
    __hip_atomic_store(p, v, __ATOMIC_RELAXED, __HIP_MEMORY_SCOPE_WORKGROUP);
}
__device__ __forceinline__ void ic_store_bf16(__bf16* p, float v) {
    unsigned u = (unsigned)__builtin_bit_cast(unsigned short, (__bf16)v);
    asm volatile("global_store_short %0, %1, off sc0 sc1" :: "v"(p), "v"(u) : "memory");
}

// ---- stager: copy chunk(s) [16 rows x 32 cols bf16] global->LDS, swizzled ----
__device__ __forceinline__ void stage_chunks4(char* buf, const char* gsrc, int c0,
                                              int row, int pc, int swz) {
    const char* g = gsrc + row * 2048 + pc * 16;
    const void* a0 = g + (size_t)(c0 + 0) * 64;
    const void* a1 = g + (size_t)(c0 + 1) * 64;
    const void* a2 = g + (size_t)(c0 + 2) * 64;
    const void* a3 = g + (size_t)(c0 + 3) * 64;
    i32x4 r0, r1, r2, r3;
    asm volatile(
        "global_load_dwordx4 %0, %4, off sc0 sc1\n\t"
        "global_load_dwordx4 %1, %5, off sc0 sc1\n\t"
        "global_load_dwordx4 %2, %6, off sc0 sc1\n\t"
        "global_load_dwordx4 %3, %7, off sc0 sc1\n\t"
        "s_waitcnt vmcnt(0)"
        : "=&v"(r0), "=&v"(r1), "=&v"(r2), "=&v"(r3)
        : "v"(a0), "v"(a1), "v"(a2), "v"(a3));
    char* d = buf + row * 64 + swz;
    *(i32x4*)(d + (c0 + 0) * 1024) = r0;
    *(i32x4*)(d + (c0 + 1) * 1024) = r1;
    *(i32x4*)(d + (c0 + 2) * 1024) = r2;
    *(i32x4*)(d + (c0 + 3) * 1024) = r3;
}
__device__ __forceinline__ void stage_chunks1(char* buf, const char* gsrc, int c,
                                              int row, int pc, int swz) {
    const void* a = gsrc + row * 2048 + (size_t)c * 64 + pc * 16;
    i32x4 r;
    asm volatile("global_load_dwordx4 %0, %1, off sc0 sc1\n\ts_waitcnt vmcnt(0)"
                 : "=&v"(r) : "v"(a));
    *(i32x4*)(buf + c * 1024 + row * 64 + swz) = r;
}

// stage one phase: wait local consumers done with buf, then stage 32 chunks
// in arrival order (chunk i ready when slots 2i and 2i+1 >= slotTarget).
__device__ __forceinline__ void stage_phase(char* buf, const char* gsrc, unsigned* slots,
                                            unsigned slotTarget, unsigned* stagedCnt,
                                            unsigned base, unsigned* doneCnt,
                                            unsigned doneTarget, int lane) {
    while (lds_ld(doneCnt) < doneTarget) { }
    const int row = lane >> 2, pc = lane & 3;
    const int swz = ((pc + (row >> 1)) & 3) << 4;
    int staged = 0;
    while (staged < 32) {
        unsigned v = __hip_atomic_load(&slots[lane * 16], __ATOMIC_RELAXED,
                                       __HIP_MEMORY_SCOPE_SYSTEM);
        unsigned long long m = __ballot((int)(v >= slotTarget));
        unsigned long long pr = m & (m >> 1) & 0x5555555555555555ull;
        unsigned long long miss = (~pr) & 0x5555555555555555ull;
        int p = miss ? (int)(__builtin_ctzll(miss) >> 1) : 32;
        if (p > staged) {
            while (staged + 4 <= p) { stage_chunks4(buf, gsrc, staged, row, pc, swz); staged += 4; }
            while (staged < p)      { stage_chunks1(buf, gsrc, staged, row, pc, swz); staged += 1; }
            asm volatile("s_waitcnt lgkmcnt(0)" ::: "memory");
            if (lane == 0) lds_st(stagedCnt, base + (unsigned)staged);
        }
    }
}

// consumer: 32 chunks, spin on LDS staged counter, MFMA per chunk (static W[i])
__device__ __forceinline__ f32x4 chunk_gemm(const char* buf, const unsigned* stagedCnt,
                                            unsigned base, const bf16x8 (&W)[32],
                                            int la, int lb) {
    const char* fb = buf + la * 64 + (((lb + (la >> 1)) & 3) << 4);
    f32x4 a0 = {0.f, 0.f, 0.f, 0.f}, a1 = a0;
    int avail = (int)(lds_ld(stagedCnt) - base);
#pragma unroll
    for (int i = 0; i < 32; ++i) {
        while (avail < i + 1) avail = (int)(lds_ld(stagedCnt) - base);
        bf16x8 a = *(const bf16x8*)(fb + i * 1024);
        if (i & 1) a1 = __builtin_amdgcn_mfma_f32_16x16x32_bf16(a, W[i], a1, 0, 0, 0);
        else       a0 = __builtin_amdgcn_mfma_f32_16x16x32_bf16(a, W[i], a0, 0, 0, 0);
    }
    return a0 + a1;
}

// wave-local transpose pack (LDS) + one wide 8B store per lane (row-major global)
__device__ __forceinline__ void pack_store_tile(__bf16* gdst, __bf16* mypack,
                                                const f32x4& v, int la, int lb, int lane) {
#pragma unroll
    for (int r = 0; r < 4; ++r) mypack[(lb * 4 + r) * 20 + la] = (__bf16)v[r];
    asm volatile("s_waitcnt lgkmcnt(0)" ::: "memory");
    __builtin_amdgcn_sched_barrier(0);
    int row = lane >> 2, cg = lane & 3;
    unsigned long long d = *(const unsigned long long*)(&mypack[row * 20 + cg * 4]);
    __bf16* dst = gdst + row * Hh + cg * 4;
    asm volatile("global_store_dwordx2 %0, %1, off sc0 sc1" :: "v"(dst), "v"(d) : "memory");
}

__global__ __launch_bounds__(NTHR, 1) void gru_v7(
    const float* __restrict__ emb, const float* __restrict__ Ww,
    const float* __restrict__ Wb, const float* __restrict__ Uw,
    const float* __restrict__ Ub, const float* __restrict__ Vw,
    const float* __restrict__ Vb,
    __bf16* __restrict__ pxi, __bf16* __restrict__ av,
    unsigned* __restrict__ arr, float* __restrict__ out)
{
    extern __shared__ char lds[];
    char* bufA   = lds;                        // 32 KB: pxi chunks
    char* bufB   = lds + 32768;                // 32 KB: av chunks
    float* p_lds = (float*)(lds + 70656);      // [16][32] f32
    f32x4* sc    = (f32x4*)(lds + 72704);      // [2][64] h handoff
    unsigned* ctr = (unsigned*)(lds + 74752);  // counters, 64B-strided
    unsigned* stagedA = ctr + 0;
    unsigned* stagedB = ctr + 16;
    unsigned* doneA   = ctr + 32;
    unsigned* doneB   = ctr + 48;
    unsigned* hcnt    = ctr + 64;              // hcnt[nt*16]

    const int tid = threadIdx.x, lane = tid & 63, wid = tid >> 6;
    const int la = lane & 15, lb = lane >> 4;
    const int wg = blockIdx.x, g = wg & 7, lw = wg >> 3;
    const int rbase = g * 16, n0 = lw * 32, nt = wid & 1;
    const int jc = n0 + nt * 16 + la;
    unsigned* slots  = arr + g * 1024;               // 64 slots x 64B stride
    unsigned* myslot = slots + (2 * lw + nt) * 16;
    __bf16* mypack = (__bf16*)(lds + 65536) + wid * 320;

    // ---- weights -> registers: 0,1<-Ww  2,3<-Vw  4,5<-Uw (full K, 32 frags) ----
    const float* wsrc = (wid < 2) ? Ww : ((wid < 4) ? Vw : Uw);
    bf16x8 Wf[32];
    if (wid < 6) {
#pragma unroll
        for (int i = 0; i < 32; ++i) {
            const float* s = wsrc + (size_t)jc * Hh + i * 32 + lb * 8;
            bf16x8 vv;
#pragma unroll
            for (int j = 0; j < 8; ++j) vv[j] = (__bf16)s[j];
            Wf[i] = vv;
        }
    }
    const float b1 = (wid < 2) ? Wb[jc] : ((wid < 4) ? Vb[jc] : Ub[jc]);
    const float b2 = Vb[jc];

    // ---- init ----
    if (tid < 96) ctr[tid] = 0;
    p_lds[tid] = 0.f;
    f32x4 pregs = {0.f, 0.f, 0.f, 0.f};
    if (wid == 4 || wid == 5) {
#pragma unroll
        for (int r = 0; r < 4; ++r) {
            int row = rbase + lb * 4 + r;
            ic_store_bf16(pxi + (size_t)row * Hh + jc, emb[(size_t)row * (Ss * Hh) + jc]);
        }
        asm volatile("s_waitcnt vmcnt(0)" ::: "memory");
        if (lane == 0)
            __hip_atomic_store(myslot, 1u, __ATOMIC_RELAXED, __HIP_MEMORY_SCOPE_SYSTEM);
    }
    __syncthreads();   // the only block barrier in the kernel

    const char* pxiG = (const char*)(pxi + (size_t)rbase * Hh);
    const char* avG  = (const char*)(av  + (size_t)rbase * Hh);

    if (wid == 7) {                      // ---- stager ----
        for (int t = 0; t < Ss; ++t) {
            stage_phase(bufA, pxiG, slots, (unsigned)(2 * t + 1), stagedA,
                        (unsigned)(32 * t), doneA, (unsigned)(4 * t), lane);
            stage_phase(bufB, avG,  slots, (unsigned)(2 * t + 2), stagedB,
                        (unsigned)(32 * t), doneB, (unsigned)(2 * t), lane);
        }
    } else if (wid < 2) {                // ---- r producer -> av ----
        __bf16* avdst = av + (size_t)rbase * Hh + n0 + nt * 16;
        for (int t = 0; t < Ss; ++t) {
            f32x4 embc;
#pragma unroll
            for (int r = 0; r < 4; ++r)
                embc[r] = emb[((size_t)(rbase + lb * 4 + r) * Ss + t) * Hh + jc];
            f32x4 acc = chunk_gemm(bufA, stagedA, (unsigned)(32 * t), Wf, la, lb);
            if (lane == 0) atomicAdd(doneA, 1u);
            f32x4 v4;
#pragma unroll
            for (int r = 0; r < 4; ++r) {
                float rg = sigmoid_fast(acc[r] + b1);
                float pc = p_lds[(lb * 4 + r) * 32 + nt * 16 + la];
                v4[r] = rg * pc + embc[r];
            }
            pack_store_tile(avdst, mypack, v4, la, lb, lane);
            asm volatile("s_waitcnt vmcnt(0)" ::: "memory");
            if (lane == 0)
                __hip_atomic_store(myslot, (unsigned)(2 * t + 2), __ATOMIC_RELAXED,
                                   __HIP_MEMORY_SCOPE_SYSTEM);
        }
    } else if (wid < 4) {                // ---- h compute -> sc handoff ----
        for (int t = 0; t < Ss; ++t) {
            f32x4 hacc = chunk_gemm(bufB, stagedB, (unsigned)(32 * t), Wf, la, lb);
            sc[nt * 64 + lane] = hacc;
            asm volatile("s_waitcnt lgkmcnt(0)" ::: "memory");
            if (lane == 0) { lds_st(&hcnt[nt * 16], (unsigned)(t + 1)); atomicAdd(doneB, 1u); }
        }
    } else if (wid < 6) {                // ---- z + state owner -> pxi, out ----
        __bf16* pxidst = pxi + (size_t)rbase * Hh + n0 + nt * 16;
        for (int t = 0; t < Ss; ++t) {
            f32x4 zacc = chunk_gemm(bufA, stagedA, (unsigned)(32 * t), Wf, la, lb);
            if (lane == 0) atomicAdd(doneA, 1u);
            f32x4 zz;
#pragma unroll
            for (int r = 0; r < 4; ++r) zz[r] = sigmoid_fast(zacc[r] + b1);
            f32x4 embn = {0.f, 0.f, 0.f, 0.f};
            if (t + 1 < Ss) {
#pragma unroll
                for (int r = 0; r < 4; ++r)
                    embn[r] = emb[((size_t)(rbase + lb * 4 + r) * Ss + (t + 1)) * Hh + jc];
            }
            while (lds_ld(&hcnt[nt * 16]) < (unsigned)(t + 1)) { }
            f32x4 hacc = sc[nt * 64 + lane];
            f32x4 pn;
#pragma unroll
            for (int r = 0; r < 4; ++r) {
                float h = tanh_fast(hacc[r] + b2);
                pn[r] = (1.f - zz[r]) * pregs[r] + zz[r] * h;
                pregs[r] = pn[r];
                p_lds[(lb * 4 + r) * 32 + nt * 16 + la] = pn[r];
            }
            if (t + 1 < Ss) {
                f32x4 px = pn + embn;
                pack_store_tile(pxidst, mypack, px, la, lb, lane);  // lgkm inside also covers p_lds
                asm volatile("s_waitcnt vmcnt(0)" ::: "memory");
                if (lane == 0)
                    __hip_atomic_store(myslot, (unsigned)(2 * t + 3), __ATOMIC_RELAXED,
                                       __HIP_MEMORY_SCOPE_SYSTEM);
            }
#pragma unroll
            for (int r = 0; r < 4; ++r)                             // shadow
                out[((size_t)(rbase + lb * 4 + r) * Ss + t) * Hh + jc] = pn[r];
        }
    }
    // wid == 6: idle
}

// ---- launch -----------------------------------------------------------------

extern "C" void kernel_launch(void* const* d_in, const int* in_sizes, int n_in,
                              void* d_out, int out_size, void* d_ws, size_t ws_size,
                              hipStream_t stream) {
    const float* emb = (const float*)d_in[0];
    const float* Ww  = (const float*)d_in[1];
    const float* Wb  = (const float*)d_in[2];
    const float* Uw  = (const float*)d_in[3];
    const float* Ub  = (const float*)d_in[4];
    const float* Vw  = (const float*)d_in[5];
    const float* Vb  = (const float*)d_in[6];
    float* out = (float*)d_out;

    char* ws = (char*)d_ws;
    __bf16*   pxi = (__bf16*)(ws);                 // 256 KB
    __bf16*   av  = (__bf16*)(ws + 256 * 1024);    // 256 KB
    unsigned* arr = (unsigned*)(ws + 512 * 1024);  // 8 groups x 64 slots x 64B = 32 KB

    hipMemsetAsync(arr, 0, 32768, stream);
    hipFuncSetAttribute(reinterpret_cast<const void*>(gru_v7),
                        hipFuncAttributeMaxDynamicSharedMemorySize, LDS_TOTAL);

    void* args[] = {(void*)&emb, (void*)&Ww, (void*)&Wb, (void*)&Uw, (void*)&Ub,
                    (void*)&Vw, (void*)&Vb, (void*)&pxi, (void*)&av,
                    (void*)&arr, (void*)&out};
    hipError_t e = hipLaunchCooperativeKernel(
        reinterpret_cast<const void*>(gru_v7), dim3(NWG), dim3(NTHR),
        args, LDS_TOTAL, stream);
    if (e != hipSuccess) {
        gru_v7<<<dim3(NWG), dim3(NTHR), LDS_TOTAL, stream>>>(
            emb, Ww, Wb, Uw, Ub, Vw, Vb, pxi, av, arr, out);
    }
}

// Round 9
// 5700.308 us; speedup vs baseline: 1.1706x; 1.1706x over previous
//
#include <hip/hip_runtime.h>
#include <hip/hip_bf16.h>

// GRU B=128, S=512, H=1024 — persistent kernel, sentinel-valued dataflow.
// 8 independent groups x 32 WGs (group = wg&7); group owns 16 batch rows; WG
// owns 32 cols. NO barriers, NO flags, NO LDS staging: exchange buffers (pxi,
// av) are 4-step-rotated, sentinel-filled (0xFFFF = bf16 NaN; data provably
// finite); producers store 8B granules (sc0 sc1, IC-coherent); consumers load
// MFMA fragments IC->registers and re-load granules still reading sentinel —
// the data load IS the barrier. Restore protocol: each producer wave sentinels
// its own slice of buf[(t+2)&3] and drains (vmcnt 0) before publishing step-t
// data; the pxi/av publication chain guarantees all consumers of that buffer
// generation finished before the restore can land (verified chain, r8 notes).
// Waves: 0/1 r (Ww, K-half each, partner-sum via LDS) -> av;  2/3 z (Uw) ->
// LDS;  4/5 h (Vw, reads av) -> LDS;  6/7 gate: p'=(1-z)p+z*tanh(h+b2), out,
// pxi' = p' + x_{t+1}. Waves 0/4 poll a 64x4B indicator row (traffic control).

#define Ss 512
#define Hh 1024
#define NWG 256
#define NTHR 512

typedef __bf16 bf16x8 __attribute__((ext_vector_type(8)));
typedef float f32x4 __attribute__((ext_vector_type(4)));
typedef int   i32x4 __attribute__((ext_vector_type(4)));

__device__ __forceinline__ float sigmoid_fast(float x) { return 1.f / (1.f + __expf(-x)); }
__device__ __forceinline__ float tanh_fast(float x) { return 2.f / (1.f + __expf(-2.f * x)) - 1.f; }

__device__ __forceinline__ unsigned lds_ld(const unsigned* p) {
    return __hip_atomic_load(p, __ATOMIC_RELAXED, __HIP_MEMORY_SCOPE_WORKGROUP);
}
__device__ __forceinline__ void lds_st(unsigned* p, unsigned v) {
    __hip_atomic_store(p, v, __ATOMIC_RELAXED, __HIP_MEMORY_SCOPE_WORKGROUP);
}
__device__ __forceinline__ void ic_store64(char* p, unsigned long long v) {
    asm volatile("global_store_dwordx2 %0, %1, off sc0 sc1" :: "v"(p), "v"(v) : "memory");
}

// poll-load 16 A-frags (one K-half, 1KB) IC->regs with sentinel re-check, then
// 32 MFMA into acc0 (n-tile 0) / acc1 (n-tile 1). a = frag base (lane ptr).
__device__ __forceinline__ void gemm_poll(const char* a,
                                          const bf16x8 (&B0)[16], const bf16x8 (&B1)[16],
                                          f32x4& acc0, f32x4& acc1)
{
    i32x4 fr[16];
    asm volatile(
        "global_load_dwordx4 %0, %16, off offset:0 sc0 sc1\n\t"
        "global_load_dwordx4 %1, %16, off offset:64 sc0 sc1\n\t"
        "global_load_dwordx4 %2, %16, off offset:128 sc0 sc1\n\t"
        "global_load_dwordx4 %3, %16, off offset:192 sc0 sc1\n\t"
        "global_load_dwordx4 %4, %16, off offset:256 sc0 sc1\n\t"
        "global_load_dwordx4 %5, %16, off offset:320 sc0 sc1\n\t"
        "global_load_dwordx4 %6, %16, off offset:384 sc0 sc1\n\t"
        "global_load_dwordx4 %7, %16, off offset:448 sc0 sc1\n\t"
        "global_load_dwordx4 %8, %16, off offset:512 sc0 sc1\n\t"
        "global_load_dwordx4 %9, %16, off offset:576 sc0 sc1\n\t"
        "global_load_dwordx4 %10, %16, off offset:640 sc0 sc1\n\t"
        "global_load_dwordx4 %11, %16, off offset:704 sc0 sc1\n\t"
        "global_load_dwordx4 %12, %16, off offset:768 sc0 sc1\n\t"
        "global_load_dwordx4 %13, %16, off offset:832 sc0 sc1\n\t"
        "global_load_dwordx4 %14, %16, off offset:896 sc0 sc1\n\t"
        "global_load_dwordx4 %15, %16, off offset:960 sc0 sc1"
        : "=&v"(fr[0]), "=&v"(fr[1]), "=&v"(fr[2]), "=&v"(fr[3]),
          "=&v"(fr[4]), "=&v"(fr[5]), "=&v"(fr[6]), "=&v"(fr[7]),
          "=&v"(fr[8]), "=&v"(fr[9]), "=&v"(fr[10]), "=&v"(fr[11]),
          "=&v"(fr[12]), "=&v"(fr[13]), "=&v"(fr[14]), "=&v"(fr[15])
        : "v"(a) : "memory");
    for (;;) {
        asm volatile("s_waitcnt vmcnt(0)" ::: "memory");
        __builtin_amdgcn_sched_barrier(0);
        unsigned bad = 0;
#pragma unroll
        for (int i = 0; i < 16; ++i)
            if (__any((int)(((fr[i][0] & 0xFFFF) == 0xFFFF) |
                            ((fr[i][2] & 0xFFFF) == 0xFFFF)))) bad |= 1u << i;
        if (!bad) break;
#define RL(I, OFF) if (bad & (1u << I)) \
        asm volatile("global_load_dwordx4 %0, %1, off offset:" OFF " sc0 sc1" \
                     : "=&v"(fr[I]) : "v"(a) : "memory");
        RL(0, "0") RL(1, "64") RL(2, "128") RL(3, "192")
        RL(4, "256") RL(5, "320") RL(6, "384") RL(7, "448")
        RL(8, "512") RL(9, "576") RL(10, "640") RL(11, "704")
        RL(12, "768") RL(13, "832") RL(14, "896") RL(15, "960")
#undef RL
    }
#pragma unroll
    for (int i = 0; i < 16; ++i) {
        bf16x8 av8 = __builtin_bit_cast(bf16x8, fr[i]);
        acc0 = __builtin_amdgcn_mfma_f32_16x16x32_bf16(av8, B0[i], acc0, 0, 0, 0);
        acc1 = __builtin_amdgcn_mfma_f32_16x16x32_bf16(av8, B1[i], acc1, 0, 0, 0);
    }
}

__global__ __launch_bounds__(NTHR, 1) void gru_v9(
    const float* __restrict__ emb, const float* __restrict__ Ww,
    const float* __restrict__ Wb, const float* __restrict__ Uw,
    const float* __restrict__ Ub, const float* __restrict__ Vw,
    const float* __restrict__ Vb,
    char* __restrict__ xbuf, char* __restrict__ abuf,
    float* __restrict__ out)
{
    __shared__ float    p_lds[16][36];
    __shared__ float    pslot[6][4][64];
    __shared__ float    zslot[2][4][64];
    __shared__ float    hslot[2][4][64];
    __shared__ unsigned flags[12][16];   // 0-5 partial, 6/7 z, 8/9 h, 10 rdyX, 11 rdyA
    __shared__ __bf16   bpack[8][16][20];
    __shared__ float    fpack[2][16][24];

    const int tid = threadIdx.x, lane = tid & 63, wid = tid >> 6;
    const int la = lane & 15, lb = lane >> 4;
    const int wg = blockIdx.x, g = wg & 7, lw = wg >> 3;
    const int rbase = g * 16, n0 = lw * 32;
    const int prow = lane >> 2, pcg = lane & 3;    // pack/store lane mapping
    char* xg = xbuf + ((size_t)g << 17);           // 4 bufs x 32KB per group
    char* ag = abuf + ((size_t)g << 17);
    const unsigned long long SENT64 = ~0ull;

    // ---- weights -> registers (B-frag layout verified r3/r4) ----
    bf16x8 B0[16], B1[16];
    float bias1 = 0.f, bias2 = 0.f;
    if (wid < 6) {
        const float* wsrc = (wid < 2) ? Ww : ((wid < 4) ? Uw : Vw);
        const int kh = wid & 1;
#pragma unroll
        for (int i = 0; i < 16; ++i) {
            const float* s0 = wsrc + (size_t)(n0 + la) * Hh      + kh * 512 + i * 32 + lb * 8;
            const float* s1 = wsrc + (size_t)(n0 + 16 + la) * Hh + kh * 512 + i * 32 + lb * 8;
            bf16x8 v0, v1;
#pragma unroll
            for (int j = 0; j < 8; ++j) { v0[j] = (__bf16)s0[j]; v1[j] = (__bf16)s1[j]; }
            B0[i] = v0; B1[i] = v1;
        }
        const int nt = wid & 1;
        if (wid < 2)      bias1 = Wb[n0 + nt * 16 + la];
        else if (wid < 4) bias1 = Ub[n0 + nt * 16 + la];
    } else {
        bias2 = Vb[n0 + (wid - 6) * 16 + la];
    }

    // ---- LDS init ----
    {
        float* pl = &p_lds[0][0];
        pl[tid] = 0.f;
        if (tid < 64) pl[512 + tid] = 0.f;
        if (tid < 192) (&flags[0][0])[tid] = 0u;
    }
    __syncthreads();

    // ---- init: pxi(0) = x_0 (p0 = 0), published by gate waves into xg buf0 ----
    f32x4 pv = {0.f, 0.f, 0.f, 0.f};
    if (wid >= 6) {
        const int nt = wid - 6;
        const int jc = n0 + nt * 16 + la;
#pragma unroll
        for (int r = 0; r < 4; ++r)
            bpack[wid][lb * 4 + r][la] =
                (__bf16)emb[((size_t)(rbase + lb * 4 + r) * Ss) * Hh + jc];
        asm volatile("s_waitcnt lgkmcnt(0)" ::: "memory");
        __builtin_amdgcn_sched_barrier(0);
        unsigned long long d = *(const unsigned long long*)&bpack[wid][prow][pcg * 4];
        ic_store64(xg + prow * 2048 + (n0 + nt * 16 + pcg * 4) * 2, d);
    }

    const int svoff_r    = prow * 2048 + (n0 + (wid & 1) * 16 + pcg * 4) * 2;       // r waves
    const int svoff_gate = prow * 2048 + (n0 + (wid - 6) * 16 + pcg * 4) * 2;       // gate waves

    // =================== roles ===================
    if (wid < 2) {                               // ---- r waves -> av ----
        const int nt = wid, kh = wid;
        const int jc = n0 + nt * 16 + la;
        const int fvoff = la * 2048 + kh * 1024 + lb * 16;
        for (int t = 0; t < Ss; ++t) {
            ic_store64(ag + (((t + 2) & 3) << 15) + svoff_r, SENT64);  // restore av slice
            f32x4 embc;
#pragma unroll
            for (int r = 0; r < 4; ++r)
                embc[r] = emb[((size_t)(rbase + lb * 4 + r) * Ss + t) * Hh + jc];
            asm volatile("s_waitcnt vmcnt(0)" ::: "memory");           // restore drained
            if (wid == 0) {                                            // pxi indicator poll
                const char* ip = xg + ((t & 3) << 15) + lane * 32;
                unsigned d;
                do {
                    asm volatile("global_load_dword %0, %1, off sc0 sc1\n\ts_waitcnt vmcnt(0)"
                                 : "=v"(d) : "v"(ip) : "memory");
                } while (__any((int)((d & 0xFFFF) == 0xFFFF)));
                lds_st(&flags[10][0], (unsigned)(t + 1));
            } else {
                while (lds_ld(&flags[10][0]) < (unsigned)(t + 1)) {}
            }
            f32x4 acc0 = {0.f,0.f,0.f,0.f}, acc1 = acc0;
            gemm_poll(xg + ((t & 3) << 15) + fvoff, B0, B1, acc0, acc1);
            f32x4 give = (wid == 0) ? acc1 : acc0;                     // partial exchange
            f32x4 mine = (wid == 0) ? acc0 : acc1;
#pragma unroll
            for (int r = 0; r < 4; ++r) pslot[wid][r][lane] = give[r];
            asm volatile("s_waitcnt lgkmcnt(0)" ::: "memory");
            lds_st(&flags[wid][0], (unsigned)(t + 1));
            while (lds_ld(&flags[wid ^ 1][0]) < (unsigned)(t + 1)) {}
            asm volatile("" ::: "memory");
#pragma unroll
            for (int r = 0; r < 4; ++r) {                              // av = sig()*p + x
                float rg = sigmoid_fast(mine[r] + pslot[wid ^ 1][r][lane] + bias1);
                float pc = p_lds[lb * 4 + r][nt * 16 + la];
                bpack[wid][lb * 4 + r][la] = (__bf16)(rg * pc + embc[r]);
            }
            asm volatile("s_waitcnt lgkmcnt(0)" ::: "memory");
            __builtin_amdgcn_sched_barrier(0);
            unsigned long long dd = *(const unsigned long long*)&bpack[wid][prow][pcg * 4];
            ic_store64(ag + ((t & 3) << 15) + svoff_r, dd);            // publish av
        }
    } else if (wid < 4) {                        // ---- z waves -> LDS ----
        const int nt = wid & 1, kh = nt;
        const int fvoff = la * 2048 + kh * 1024 + lb * 16;
        for (int t = 0; t < Ss; ++t) {
            while (lds_ld(&flags[10][0]) < (unsigned)(t + 1)) {}
            f32x4 acc0 = {0.f,0.f,0.f,0.f}, acc1 = acc0;
            gemm_poll(xg + ((t & 3) << 15) + fvoff, B0, B1, acc0, acc1);
            f32x4 give = (nt == 0) ? acc1 : acc0;
            f32x4 mine = (nt == 0) ? acc0 : acc1;
#pragma unroll
            for (int r = 0; r < 4; ++r) pslot[wid][r][lane] = give[r];
            asm volatile("s_waitcnt lgkmcnt(0)" ::: "memory");
            lds_st(&flags[wid][0], (unsigned)(t + 1));
            while (lds_ld(&flags[wid ^ 1][0]) < (unsigned)(t + 1)) {}
            asm volatile("" ::: "memory");
#pragma unroll
            for (int r = 0; r < 4; ++r)
                zslot[nt][r][lane] = sigmoid_fast(mine[r] + pslot[wid ^ 1][r][lane] + bias1);
            asm volatile("s_waitcnt lgkmcnt(0)" ::: "memory");
            lds_st(&flags[6 + nt][0], (unsigned)(t + 1));
        }
    } else if (wid < 6) {                        // ---- h waves -> LDS ----
        const int nt = wid & 1, kh = nt;
        const int fvoff = la * 2048 + kh * 1024 + lb * 16;
        for (int t = 0; t < Ss; ++t) {
            if (wid == 4) {                                            // av indicator poll
                const char* ip = ag + ((t & 3) << 15) + lane * 32;
                unsigned d;
                do {
                    asm volatile("global_load_dword %0, %1, off sc0 sc1\n\ts_waitcnt vmcnt(0)"
                                 : "=v"(d) : "v"(ip) : "memory");
                } while (__any((int)((d & 0xFFFF) == 0xFFFF)));
                lds_st(&flags[11][0], (unsigned)(t + 1));
            } else {
                while (lds_ld(&flags[11][0]) < (unsigned)(t + 1)) {}
            }
            f32x4 acc0 = {0.f,0.f,0.f,0.f}, acc1 = acc0;
            gemm_poll(ag + ((t & 3) << 15) + fvoff, B0, B1, acc0, acc1);
            f32x4 give = (nt == 0) ? acc1 : acc0;
            f32x4 mine = (nt == 0) ? acc0 : acc1;
#pragma unroll
            for (int r = 0; r < 4; ++r) pslot[wid][r][lane] = give[r];
            asm volatile("s_waitcnt lgkmcnt(0)" ::: "memory");
            lds_st(&flags[wid][0], (unsigned)(t + 1));
            while (lds_ld(&flags[wid ^ 1][0]) < (unsigned)(t + 1)) {}
            asm volatile("" ::: "memory");
#pragma unroll
            for (int r = 0; r < 4; ++r)
                hslot[nt][r][lane] = mine[r] + pslot[wid ^ 1][r][lane];
            asm volatile("s_waitcnt lgkmcnt(0)" ::: "memory");
            lds_st(&flags[8 + nt][0], (unsigned)(t + 1));
        }
    } else {                                     // ---- gate waves ----
        const int nt = wid - 6;
        const int jc = n0 + nt * 16 + la;
        for (int t = 0; t < Ss; ++t) {
            ic_store64(xg + (((t + 2) & 3) << 15) + svoff_gate, SENT64); // restore pxi slice
            f32x4 embn = {0.f,0.f,0.f,0.f};
            if (t + 1 < Ss) {
#pragma unroll
                for (int r = 0; r < 4; ++r)
                    embn[r] = emb[((size_t)(rbase + lb * 4 + r) * Ss + (t + 1)) * Hh + jc];
            }
            asm volatile("s_waitcnt vmcnt(0)" ::: "memory");             // restore drained
            while (lds_ld(&flags[6 + nt][0]) < (unsigned)(t + 1)) {}
            asm volatile("" ::: "memory");
            f32x4 zz;
#pragma unroll
            for (int r = 0; r < 4; ++r) zz[r] = zslot[nt][r][lane];
            while (lds_ld(&flags[8 + nt][0]) < (unsigned)(t + 1)) {}
            asm volatile("" ::: "memory");
            f32x4 pn;
#pragma unroll
            for (int r = 0; r < 4; ++r) {
                float h = tanh_fast(hslot[nt][r][lane] + bias2);
                pn[r] = (1.f - zz[r]) * pv[r] + zz[r] * h;
                pv[r] = pn[r];
                p_lds[lb * 4 + r][nt * 16 + la] = pn[r];
            }
            if (t + 1 < Ss) {
#pragma unroll
                for (int r = 0; r < 4; ++r)
                    bpack[wid][lb * 4 + r][la] = (__bf16)(pn[r] + embn[r]);
                asm volatile("s_waitcnt lgkmcnt(0)" ::: "memory");  // p_lds+pack committed
                __builtin_amdgcn_sched_barrier(0);
                unsigned long long dd = *(const unsigned long long*)&bpack[wid][prow][pcg * 4];
                ic_store64(xg + (((t + 1) & 3) << 15) + svoff_gate, dd); // publish pxi(t+1)
            }
#pragma unroll
            for (int r = 0; r < 4; ++r) fpack[nt][lb * 4 + r][la] = pn[r];
            asm volatile("s_waitcnt lgkmcnt(0)" ::: "memory");
            __builtin_amdgcn_sched_barrier(0);
            f32x4 ov = *(const f32x4*)&fpack[nt][prow][pcg * 4];
            *(f32x4*)(out + ((size_t)(rbase + prow) * Ss + t) * Hh + n0 + nt * 16 + pcg * 4) = ov;
        }
    }
}

// ---- launch -----------------------------------------------------------------

extern "C" void kernel_launch(void* const* d_in, const int* in_sizes, int n_in,
                              void* d_out, int out_size, void* d_ws, size_t ws_size,
                              hipStream_t stream) {
    const float* emb = (const float*)d_in[0];
    const float* Ww  = (const float*)d_in[1];
    const float* Wb  = (const float*)d_in[2];
    const float* Uw  = (const float*)d_in[3];
    const float* Ub  = (const float*)d_in[4];
    const float* Vw  = (const float*)d_in[5];
    const float* Vb  = (const float*)d_in[6];
    float* out = (float*)d_out;

    char* xbuf = (char*)d_ws;                          // 1 MB: 8 groups x 4 x 32KB
    char* abuf = (char*)d_ws + (1 << 20);              // 1 MB

    // sentinel-fill both exchange regions (bf16 0xFFFF = NaN) each call
    hipMemsetAsync(d_ws, 0xFF, 2u << 20, stream);

    void* args[] = {(void*)&emb, (void*)&Ww, (void*)&Wb, (void*)&Uw, (void*)&Ub,
                    (void*)&Vw, (void*)&Vb, (void*)&xbuf, (void*)&abuf, (void*)&out};
    hipError_t e = hipLaunchCooperativeKernel(
        reinterpret_cast<const void*>(gru_v9), dim3(NWG), dim3(NTHR),
        args, 0, stream);
    if (e != hipSuccess) {
        gru_v9<<<dim3(NWG), dim3(NTHR), 0, stream>>>(
            emb, Ww, Wb, Uw, Ub, Vw, Vb, xbuf, abuf, out);
    }
}